// Round 19
// baseline (300.489 us; speedup 1.0000x reference)
//
#include <hip/hip_runtime.h>
#include <hip/hip_bf16.h>

#define T_DIM 2048
#define N_DIM 256
#define K_DIM 256
#define C_DIM 40
#define CHUNK 32
#define NCHUNK 64                     // T_DIM / CHUNK

#define LOG2E_F 1.44269504088896340736f
#define LN2_F   0.69314718055994530942f
#define NEGBIG  (-1.0e30f)

typedef short bf16x8 __attribute__((ext_vector_type(8)));
typedef float f32x4  __attribute__((ext_vector_type(4)));

__device__ __forceinline__ float fexp2(float x) { return exp2f(x); }
__device__ __forceinline__ float flog2(float x) { return log2f(x); }
__device__ __forceinline__ float frcp(float x) { return __frcp_rn(x); }

__device__ __forceinline__ unsigned int pk2(float a, float b)
{
    __hip_bfloat162 h = __float22bfloat162_rn(make_float2(a, b));
    unsigned int r;
    __builtin_memcpy(&r, &h, sizeof(r));
    return r;
}

__device__ __forceinline__ uint4 pack8u(float4 lo, float4 hi)
{
    uint4 t;
    t.x = pk2(lo.x, lo.y);
    t.y = pk2(lo.z, lo.w);
    t.z = pk2(hi.x, hi.y);
    t.w = pk2(hi.z, hi.w);
    return t;
}

__device__ __forceinline__ bf16x8 as_bf16x8(uint4 u)
{
    bf16x8 r;
    __builtin_memcpy(&r, &u, sizeof(r));
    return r;
}

__device__ __forceinline__ unsigned short bf16r(float v)
{
    return (unsigned short)(pk2(v, 0.0f) & 0xffffu);
}

__device__ __forceinline__ float bl(unsigned int w) { return __uint_as_float(w << 16); }
__device__ __forceinline__ float bh(unsigned int w) { return __uint_as_float(w & 0xffff0000u); }

__device__ __forceinline__ float tanh5(float v)
{
    const float e = fexp2(fabsf(v) * (2.0f * LOG2E_F)); // e^(2|v|)
    const float t = 1.0f - 2.0f * frcp(e + 1.0f);       // tanh(|v|)
    return 5.0f * copysignf(t, v);
}

// ---------------------------------------------------------------------------
// K1: R13's structure (2mt x 2kh waves, 32-row tiles, gload_lds, both-sides
// unit swizzle, counted vmcnt) DEEPENED to a 4-buffer pipeline: 134 KB LDS
// -> 1 block/CU, 3 prefetch tiles in flight = 96 KB/CU outstanding (1.5x
// R13's 64 KB). vmcnt at B2: kh0 waits (28) = 2 stage-batches(16) + 12
// stores newer than the needed batch; kh1 waits (16). Buffer reuse distance
// = 3 barriers, so reads long complete before overwrite. Grid 256 = 1
// block/CU, 64 tiles each, balanced.
// ---------------------------------------------------------------------------
__global__ __launch_bounds__(256) void k1_gemm_tanh(
    const float* __restrict__ x, const float* __restrict__ W,
    const float* __restrict__ b, unsigned short* __restrict__ yb)
{
    __shared__ __align__(16) float xl[4][32 * 256];   // 4 x 32 KB fp32 (unit-swizzled)
    __shared__ __align__(16) float pl[2][12 * 64];    // 6 KB partials [mt][j*64+lane]

    const int tid  = threadIdx.x;
    const int wave = tid >> 6;
    const int lane = tid & 63;
    const int lr   = lane & 15;
    const int kg   = lane >> 4;
    const int mt   = wave & 1;    // M-tile: rows mt*16 .. +16
    const int kh   = wave >> 1;   // K-half: ks in [kh*4, kh*4+4)

    const float bc0 = b[lr];
    const float bc1 = b[16 + lr];
    const float bc2 = (lr < 8) ? b[32 + lr] : 0.0f;

    bf16x8 wf[4][3];
#pragma unroll
    for (int i = 0; i < 4; ++i) {
        const int ks = kh * 4 + i;
#pragma unroll
        for (int nt = 0; nt < 3; ++nt) {
            const int col = nt * 16 + lr;
            float4 lo = make_float4(0, 0, 0, 0), hi = lo;
            if (col < C_DIM) {
                const float* wp = W + (size_t)col * K_DIM + ks * 32 + kg * 8;
                lo = *(const float4*)wp;
                hi = *(const float4*)(wp + 4);
            }
            wf[i][nt] = as_bf16x8(pack8u(lo, hi));
        }
    }

#define STAGE(buf, st_)                                                        \
    {                                                                          \
        _Pragma("unroll")                                                      \
        for (int p = 0; p < 8; ++p) {                                          \
            const int r = wave * 8 + p;                                        \
            const float* gp = x + ((size_t)(st_) * 32 + r) * 256               \
                                + ((lane ^ (r & 7)) << 2);                     \
            __builtin_amdgcn_global_load_lds(                                  \
                (const __attribute__((address_space(1))) unsigned int*)gp,     \
                (__attribute__((address_space(3))) unsigned int*)&xl[buf][r * 256], \
                16, 0, 0);                                                     \
        }                                                                      \
    }

    const int rr = mt * 16 + lr;
    const int sw = lr & 7;

    // ---- prologue: stage tiles 0,1,2 (24 gloads/wave); land buf0 ----
    int st = blockIdx.x;
    STAGE(0, st)
    STAGE(1, st + 256)
    STAGE(2, st + 512)
    asm volatile("s_waitcnt vmcnt(16)" ::: "memory");
    __builtin_amdgcn_s_barrier();

#pragma unroll 1
    for (int t = 0; t < 64; ++t, st += 256) {
        if (t + 3 < 64) STAGE((t + 3) & 3, st + 768)

        f32x4 af0, af1, af2;
        if (kh == 0) {
            af0 = (f32x4){bc0, bc0, bc0, bc0};
            af1 = (f32x4){bc1, bc1, bc1, bc1};
            af2 = (f32x4){bc2, bc2, bc2, bc2};
        } else {
            af0 = (f32x4){0.f, 0.f, 0.f, 0.f}; af1 = af0; af2 = af0;
        }
        const float* rowp = &xl[t & 3][rr * 256];
#pragma unroll
        for (int i = 0; i < 4; ++i) {
            const int u0 = (kh * 4 + i) * 8 + kg * 2;
            const float4 lo = *(const float4*)(rowp + ((u0 ^ sw) << 2));
            const float4 hi = *(const float4*)(rowp + (((u0 + 1) ^ sw) << 2));
            const bf16x8 a = as_bf16x8(pack8u(lo, hi));
            af0 = __builtin_amdgcn_mfma_f32_16x16x32_bf16(a, wf[i][0], af0, 0, 0, 0);
            af1 = __builtin_amdgcn_mfma_f32_16x16x32_bf16(a, wf[i][1], af1, 0, 0, 0);
            af2 = __builtin_amdgcn_mfma_f32_16x16x32_bf16(a, wf[i][2], af2, 0, 0, 0);
        }

        if (kh == 1) {      // publish upper-K partials: pl[mt][j*64+lane]
            float* p = &pl[mt][lane];
#pragma unroll
            for (int j = 0; j < 4; ++j) p[j * 64]       = af0[j];
#pragma unroll
            for (int j = 0; j < 4; ++j) p[(4 + j) * 64] = af1[j];
#pragma unroll
            for (int j = 0; j < 4; ++j) p[(8 + j) * 64] = af2[j];
        }
        asm volatile("s_waitcnt lgkmcnt(0)" ::: "memory");
        __builtin_amdgcn_s_barrier();      // B1: pl visible; xl[t&3] reads done

        if (kh == 0) {     // combine + epilogue (12 stores)
            const float* p = &pl[mt][lane];
            unsigned short* yr =
                yb + ((size_t)st * 32 + mt * 16 + kg * 4) * C_DIM;
#pragma unroll
            for (int r = 0; r < 4; ++r) {
                yr[r * C_DIM + lr]      = bf16r(tanh5(af0[r] + p[r * 64]));
                yr[r * C_DIM + 16 + lr] = bf16r(tanh5(af1[r] + p[(4 + r) * 64]));
                if (lr < 8)
                    yr[r * C_DIM + 32 + lr] = bf16r(tanh5(af2[r] + p[(8 + r) * 64]));
            }
            // in-order vmcnt: oldest-needed batch (next tile's 8 gloads,
            // issued 3 iterations back) retired iff outstanding <= 2 newer
            // stage batches (16) + these 12 stores = 28.
            asm volatile("s_waitcnt vmcnt(28)" ::: "memory");
        } else {
            asm volatile("s_waitcnt vmcnt(16)" ::: "memory");
        }
        __builtin_amdgcn_s_barrier();      // B2: next tile fully staged
    }
#undef STAGE
}

// ---------------------------------------------------------------------------
// K2: R13 VERBATIM — per (chain n, chunk g) propagate the 8x8 log-semiring
// matrix through 32 steps; y bf16. (R18's 128x16 split regressed: +27us.)
// ---------------------------------------------------------------------------
__global__ __launch_bounds__(256) void k2_chunks(
    const unsigned short* __restrict__ yb, float* __restrict__ cmat)
{
    const int tid  = threadIdx.x;
    const int wave = tid >> 6;
    const int lane = tid & 63;
    const int task = lane >> 3;   // 8 tasks per wave
    const int c    = lane & 7;    // column owned by this lane
    const int g    = blockIdx.x & (NCHUNK - 1);
    const int n    = ((blockIdx.x >> 6) << 5) + (wave << 3) + task;

    float col[8];
#pragma unroll
    for (int j = 0; j < 8; ++j) col[j] = (j == c) ? 0.0f : NEGBIG;

    const unsigned short* __restrict__ yp =
        yb + ((size_t)(g * CHUNK) * N_DIM + (size_t)n) * C_DIM;

#pragma unroll 1
    for (int s = 0; s < CHUNK; ++s) {
        float sc[C_DIM];
        const uint4* p4 = (const uint4*)yp;
#pragma unroll
        for (int q = 0; q < 5; ++q) {
            const uint4 u = p4[q];
            sc[8 * q + 0] = bl(u.x) * LOG2E_F;
            sc[8 * q + 1] = bh(u.x) * LOG2E_F;
            sc[8 * q + 2] = bl(u.y) * LOG2E_F;
            sc[8 * q + 3] = bh(u.y) * LOG2E_F;
            sc[8 * q + 4] = bl(u.z) * LOG2E_F;
            sc[8 * q + 5] = bh(u.z) * LOG2E_F;
            sc[8 * q + 6] = bl(u.w) * LOG2E_F;
            sc[8 * q + 7] = bh(u.w) * LOG2E_F;
        }
        float nc[8];
#pragma unroll
        for (int d = 0; d < 4; ++d) {          // dense rows: lse over 8
            float tv[8];
#pragma unroll
            for (int j = 0; j < 8; ++j) tv[j] = sc[d * 8 + j] + col[j];
            float m = tv[0];
#pragma unroll
            for (int j = 1; j < 8; ++j) m = fmaxf(m, tv[j]);
            float ss = 0.0f;
#pragma unroll
            for (int j = 0; j < 8; ++j) ss += fexp2(tv[j] - m);
            nc[d] = m + flog2(ss);
        }
#pragma unroll
        for (int i = 0; i < 4; ++i) {          // sparse rows: logaddexp of 2
            const float a  = sc[32 + i] + col[i];
            const float bb = sc[36 + i] + col[i + 4];
            const float m  = fmaxf(a, bb);
            const float ss = fexp2(a - m) + fexp2(bb - m);
            nc[4 + i] = m + flog2(ss);
        }
#pragma unroll
        for (int j = 0; j < 8; ++j) col[j] = nc[j];
        yp += (size_t)N_DIM * C_DIM;
    }
    // store M[j][c] at cmat[((g*8 + c)*N_DIM + n)*8 + j]
    float* __restrict__ op = cmat + (((size_t)g * 8 + c) * N_DIM + n) * 8;
#pragma unroll
    for (int j = 0; j < 8; ++j) op[j] = col[j];
}

// ---------------------------------------------------------------------------
// K3: R13 VERBATIM — fold the 64 chunk matrices into logZ.
// ---------------------------------------------------------------------------
__global__ __launch_bounds__(256) void k3_combine(
    const float* __restrict__ cmat, float* __restrict__ corr)
{
    const int tid = threadIdx.x;
    const int d   = tid & 7;
    const int n   = blockIdx.x * 32 + (tid >> 3);

    float v[8];
#pragma unroll
    for (int j = 0; j < 8; ++j) v[j] = 0.0f;

#pragma unroll 1
    for (int g = 0; g < NCHUNK; ++g) {
        const float* mg = cmat + ((size_t)g * 8 * N_DIM + n) * 8 + d;
        float mm[8];
#pragma unroll
        for (int j = 0; j < 8; ++j) mm[j] = mg[(size_t)j * N_DIM * 8];
        float tv[8];
#pragma unroll
        for (int j = 0; j < 8; ++j) tv[j] = mm[j] + v[j];
        float m = tv[0];
#pragma unroll
        for (int j = 1; j < 8; ++j) m = fmaxf(m, tv[j]);
        float ss = 0.0f;
#pragma unroll
        for (int j = 0; j < 8; ++j) ss += fexp2(tv[j] - m);
        const float nv = m + flog2(ss);
#pragma unroll
        for (int j = 0; j < 8; ++j) v[j] = __shfl(nv, j, 8);
    }
    float m = v[0];
#pragma unroll
    for (int j = 1; j < 8; ++j) m = fmaxf(m, v[j]);
    float ss = 0.0f;
#pragma unroll
    for (int j = 0; j < 8; ++j) ss += fexp2(v[j] - m);
    const float lz2 = m + flog2(ss);                 // base-2 logZ
    if (d == 0) corr[n] = lz2 * LN2_F / (float)T_DIM;
}

// ---------------------------------------------------------------------------
// K4: out[t][n][c] = f32(yb[t][n][c]) - corr[n]
// ---------------------------------------------------------------------------
__global__ __launch_bounds__(256) void k4_final(
    const unsigned short* __restrict__ yb, const float* __restrict__ corr,
    float* __restrict__ out)
{
    const int i = blockIdx.x * 256 + threadIdx.x;    // 8-elem group index
    const uint4 u = ((const uint4*)yb)[i];
    const float cr = corr[(i / 5) & (N_DIM - 1)];    // 5 groups per row
    float4 o0, o1;
    o0.x = bl(u.x) - cr; o0.y = bh(u.x) - cr;
    o0.z = bl(u.y) - cr; o0.w = bh(u.y) - cr;
    o1.x = bl(u.z) - cr; o1.y = bh(u.z) - cr;
    o1.z = bl(u.w) - cr; o1.w = bh(u.w) - cr;
    float4* o4 = (float4*)out;
    o4[i * 2]     = o0;
    o4[i * 2 + 1] = o1;
}

// ---------------------------------------------------------------------------
extern "C" void kernel_launch(void* const* d_in, const int* in_sizes, int n_in,
                              void* d_out, int out_size, void* d_ws, size_t ws_size,
                              hipStream_t stream)
{
    const float* x = (const float*)d_in[0];
    const float* W = (const float*)d_in[1];
    const float* b = (const float*)d_in[2];
    float* out = (float*)d_out;

    unsigned short* ybf = (unsigned short*)d_ws;              // 40 MB bf16 y
    float* cmat = (float*)((char*)d_ws + (48u << 20));        // 4 MB
    float* corr = cmat + (size_t)NCHUNK * 8 * N_DIM * 8;

    hipLaunchKernelGGL(k1_gemm_tanh, dim3(256),  dim3(256), 0, stream, x, W, b, ybf);
    hipLaunchKernelGGL(k2_chunks,    dim3(512),  dim3(256), 0, stream, ybf, cmat);
    hipLaunchKernelGGL(k3_combine,   dim3(8),    dim3(256), 0, stream, cmat, corr);
    hipLaunchKernelGGL(k4_final,     dim3(T_DIM * N_DIM * C_DIM / 8 / 256),
                       dim3(256), 0, stream, ybf, corr, out);
}

// Round 20
// 245.854 us; speedup vs baseline: 1.2222x; 1.2222x over previous
//
#include <hip/hip_runtime.h>
#include <hip/hip_bf16.h>

#define T_DIM 2048
#define N_DIM 256
#define K_DIM 256
#define C_DIM 40
#define CHUNK 32
#define NCHUNK 64                     // T_DIM / CHUNK

#define LOG2E_F 1.44269504088896340736f
#define LN2_F   0.69314718055994530942f
#define NEGBIG  (-1.0e30f)

typedef short bf16x8 __attribute__((ext_vector_type(8)));
typedef float f32x4  __attribute__((ext_vector_type(4)));

__device__ __forceinline__ float fexp2(float x) { return exp2f(x); }
__device__ __forceinline__ float flog2(float x) { return log2f(x); }
__device__ __forceinline__ float frcp(float x) { return __frcp_rn(x); }

__device__ __forceinline__ unsigned int pk2(float a, float b)
{
    __hip_bfloat162 h = __float22bfloat162_rn(make_float2(a, b));
    unsigned int r;
    __builtin_memcpy(&r, &h, sizeof(r));
    return r;
}

__device__ __forceinline__ uint4 pack8u(float4 lo, float4 hi)
{
    uint4 t;
    t.x = pk2(lo.x, lo.y);
    t.y = pk2(lo.z, lo.w);
    t.z = pk2(hi.x, hi.y);
    t.w = pk2(hi.z, hi.w);
    return t;
}

__device__ __forceinline__ bf16x8 as_bf16x8(uint4 u)
{
    bf16x8 r;
    __builtin_memcpy(&r, &u, sizeof(r));
    return r;
}

__device__ __forceinline__ unsigned short bf16r(float v)
{
    return (unsigned short)(pk2(v, 0.0f) & 0xffffu);
}

__device__ __forceinline__ float bl(unsigned int w) { return __uint_as_float(w << 16); }
__device__ __forceinline__ float bh(unsigned int w) { return __uint_as_float(w & 0xffff0000u); }

__device__ __forceinline__ float tanh5(float v)
{
    const float e = fexp2(fabsf(v) * (2.0f * LOG2E_F)); // e^(2|v|)
    const float t = 1.0f - 2.0f * frcp(e + 1.0f);       // tanh(|v|)
    return 5.0f * copysignf(t, v);
}

// ---------------------------------------------------------------------------
// K1: yb[row][c] = bf16(5*tanh(dot(x[row], W[c]) + b[c]))  via bf16 MFMA.
// R13 VERBATIM — best measured config (total 246.6us). global_load_lds
// 2-phase pipeline with counted vmcnt (loads stay in flight across raw
// s_barriers); fp32 staged, bf16-packed at read; both-sides 16B-unit
// swizzle (gload src unit = lane ^ (row&7); read unit = u ^ (lr&7)).
// 4 waves = 2 M-tiles x 2 K-halves; LDS 2x32KB + 6KB = 70KB -> 2
// blocks/CU; grid 512 = all resident, 32 tiles/block, balanced.
// Structural ceiling: in-flight/CU = 2 blk x 32KB prefetch = 64KB ->
// ~3.4 TB/s staging (R5-R19 sweep: every alternative structure regresses).
// ---------------------------------------------------------------------------
__global__ __launch_bounds__(256, 2) void k1_gemm_tanh(
    const float* __restrict__ x, const float* __restrict__ W,
    const float* __restrict__ b, unsigned short* __restrict__ yb)
{
    __shared__ __align__(16) float xl[2][32 * 256];   // 2 x 32 KB fp32 (unit-swizzled)
    __shared__ __align__(16) float pl[2][12 * 64];    // 6 KB partials [mt][j*64+lane]

    const int tid  = threadIdx.x;
    const int wave = tid >> 6;
    const int lane = tid & 63;
    const int lr   = lane & 15;
    const int kg   = lane >> 4;
    const int mt   = wave & 1;    // M-tile: rows mt*16 .. +16
    const int kh   = wave >> 1;   // K-half: ks in [kh*4, kh*4+4)

    const float bc0 = b[lr];
    const float bc1 = b[16 + lr];
    const float bc2 = (lr < 8) ? b[32 + lr] : 0.0f;

    bf16x8 wf[4][3];
#pragma unroll
    for (int i = 0; i < 4; ++i) {
        const int ks = kh * 4 + i;
#pragma unroll
        for (int nt = 0; nt < 3; ++nt) {
            const int col = nt * 16 + lr;
            float4 lo = make_float4(0, 0, 0, 0), hi = lo;
            if (col < C_DIM) {
                const float* wp = W + (size_t)col * K_DIM + ks * 32 + kg * 8;
                lo = *(const float4*)wp;
                hi = *(const float4*)(wp + 4);
            }
            wf[i][nt] = as_bf16x8(pack8u(lo, hi));
        }
    }

#define STAGE(buf, st_)                                                        \
    {                                                                          \
        _Pragma("unroll")                                                      \
        for (int p = 0; p < 8; ++p) {                                          \
            const int r = wave * 8 + p;                                        \
            const float* gp = x + ((size_t)(st_) * 32 + r) * 256               \
                                + ((lane ^ (r & 7)) << 2);                     \
            __builtin_amdgcn_global_load_lds(                                  \
                (const __attribute__((address_space(1))) unsigned int*)gp,     \
                (__attribute__((address_space(3))) unsigned int*)&xl[buf][r * 256], \
                16, 0, 0);                                                     \
        }                                                                      \
    }

    const int rr = mt * 16 + lr;
    const int sw = lr & 7;

    int st = blockIdx.x;
    STAGE(0, st)
    asm volatile("s_waitcnt vmcnt(0)" ::: "memory");
    __builtin_amdgcn_s_barrier();

    int cur = 0;
#pragma unroll 1
    for (int t = 0; t < 32; ++t, st += 512) {
        if (t + 1 < 32) STAGE(cur ^ 1, st + 512)

        f32x4 af0, af1, af2;
        if (kh == 0) {
            af0 = (f32x4){bc0, bc0, bc0, bc0};
            af1 = (f32x4){bc1, bc1, bc1, bc1};
            af2 = (f32x4){bc2, bc2, bc2, bc2};
        } else {
            af0 = (f32x4){0.f, 0.f, 0.f, 0.f}; af1 = af0; af2 = af0;
        }
        const float* rowp = &xl[cur][rr * 256];
#pragma unroll
        for (int i = 0; i < 4; ++i) {
            const int u0 = (kh * 4 + i) * 8 + kg * 2;
            const float4 lo = *(const float4*)(rowp + ((u0 ^ sw) << 2));
            const float4 hi = *(const float4*)(rowp + (((u0 + 1) ^ sw) << 2));
            const bf16x8 a = as_bf16x8(pack8u(lo, hi));
            af0 = __builtin_amdgcn_mfma_f32_16x16x32_bf16(a, wf[i][0], af0, 0, 0, 0);
            af1 = __builtin_amdgcn_mfma_f32_16x16x32_bf16(a, wf[i][1], af1, 0, 0, 0);
            af2 = __builtin_amdgcn_mfma_f32_16x16x32_bf16(a, wf[i][2], af2, 0, 0, 0);
        }

        if (kh == 1) {      // publish upper-K partials: pl[mt][j*64+lane]
            float* p = &pl[mt][lane];
#pragma unroll
            for (int j = 0; j < 4; ++j) p[j * 64]       = af0[j];
#pragma unroll
            for (int j = 0; j < 4; ++j) p[(4 + j) * 64] = af1[j];
#pragma unroll
            for (int j = 0; j < 4; ++j) p[(8 + j) * 64] = af2[j];
        }
        asm volatile("s_waitcnt lgkmcnt(0)" ::: "memory");
        __builtin_amdgcn_s_barrier();      // B1: pl visible; xl[cur] reads done

        if (kh == 0) {     // combine + epilogue (12 store insts)
            const float* p = &pl[mt][lane];
            unsigned short* yr =
                yb + ((size_t)st * 32 + mt * 16 + kg * 4) * C_DIM;
#pragma unroll
            for (int r = 0; r < 4; ++r) {
                yr[r * C_DIM + lr]      = bf16r(tanh5(af0[r] + p[r * 64]));
                yr[r * C_DIM + 16 + lr] = bf16r(tanh5(af1[r] + p[(4 + r) * 64]));
                if (lr < 8)
                    yr[r * C_DIM + 32 + lr] = bf16r(tanh5(af2[r] + p[(8 + r) * 64]));
            }
            // 8 gloads are OLDEST, 12 stores newest; vmcnt retires in order:
            // <=12 outstanding  =>  all gloads landed in LDS.
            asm volatile("s_waitcnt vmcnt(12)" ::: "memory");
        } else {
            asm volatile("s_waitcnt vmcnt(0)" ::: "memory");
        }
        __builtin_amdgcn_s_barrier();      // B2: next tile fully staged
        cur ^= 1;
    }
#undef STAGE
}

// ---------------------------------------------------------------------------
// K2: per (chain n, chunk g) propagate the 8x8 log-semiring matrix through
// 32 steps; y bf16 (5 x uint4 loads, shift-unpack). Base-2 domain.
// (R18's 128x16 split regressed +27us: per-chunk overhead + deeper K3 fold.)
// ---------------------------------------------------------------------------
__global__ __launch_bounds__(256) void k2_chunks(
    const unsigned short* __restrict__ yb, float* __restrict__ cmat)
{
    const int tid  = threadIdx.x;
    const int wave = tid >> 6;
    const int lane = tid & 63;
    const int task = lane >> 3;   // 8 tasks per wave
    const int c    = lane & 7;    // column owned by this lane
    const int g    = blockIdx.x & (NCHUNK - 1);
    const int n    = ((blockIdx.x >> 6) << 5) + (wave << 3) + task;

    float col[8];
#pragma unroll
    for (int j = 0; j < 8; ++j) col[j] = (j == c) ? 0.0f : NEGBIG;

    const unsigned short* __restrict__ yp =
        yb + ((size_t)(g * CHUNK) * N_DIM + (size_t)n) * C_DIM;

#pragma unroll 1
    for (int s = 0; s < CHUNK; ++s) {
        float sc[C_DIM];
        const uint4* p4 = (const uint4*)yp;
#pragma unroll
        for (int q = 0; q < 5; ++q) {
            const uint4 u = p4[q];
            sc[8 * q + 0] = bl(u.x) * LOG2E_F;
            sc[8 * q + 1] = bh(u.x) * LOG2E_F;
            sc[8 * q + 2] = bl(u.y) * LOG2E_F;
            sc[8 * q + 3] = bh(u.y) * LOG2E_F;
            sc[8 * q + 4] = bl(u.z) * LOG2E_F;
            sc[8 * q + 5] = bh(u.z) * LOG2E_F;
            sc[8 * q + 6] = bl(u.w) * LOG2E_F;
            sc[8 * q + 7] = bh(u.w) * LOG2E_F;
        }
        float nc[8];
#pragma unroll
        for (int d = 0; d < 4; ++d) {          // dense rows: lse over 8
            float tv[8];
#pragma unroll
            for (int j = 0; j < 8; ++j) tv[j] = sc[d * 8 + j] + col[j];
            float m = tv[0];
#pragma unroll
            for (int j = 1; j < 8; ++j) m = fmaxf(m, tv[j]);
            float ss = 0.0f;
#pragma unroll
            for (int j = 0; j < 8; ++j) ss += fexp2(tv[j] - m);
            nc[d] = m + flog2(ss);
        }
#pragma unroll
        for (int i = 0; i < 4; ++i) {          // sparse rows: logaddexp of 2
            const float a  = sc[32 + i] + col[i];
            const float bb = sc[36 + i] + col[i + 4];
            const float m  = fmaxf(a, bb);
            const float ss = fexp2(a - m) + fexp2(bb - m);
            nc[4 + i] = m + flog2(ss);
        }
#pragma unroll
        for (int j = 0; j < 8; ++j) col[j] = nc[j];
        yp += (size_t)N_DIM * C_DIM;
    }
    // store M[j][c] at cmat[((g*8 + c)*N_DIM + n)*8 + j]
    float* __restrict__ op = cmat + (((size_t)g * 8 + c) * N_DIM + n) * 8;
#pragma unroll
    for (int j = 0; j < 8; ++j) op[j] = col[j];
}

// ---------------------------------------------------------------------------
// K3: per chain, fold the 64 chunk matrices into logZ.
// ---------------------------------------------------------------------------
__global__ __launch_bounds__(256) void k3_combine(
    const float* __restrict__ cmat, float* __restrict__ corr)
{
    const int tid = threadIdx.x;
    const int d   = tid & 7;
    const int n   = blockIdx.x * 32 + (tid >> 3);

    float v[8];
#pragma unroll
    for (int j = 0; j < 8; ++j) v[j] = 0.0f;

#pragma unroll 1
    for (int g = 0; g < NCHUNK; ++g) {
        const float* mg = cmat + ((size_t)g * 8 * N_DIM + n) * 8 + d;
        float mm[8];
#pragma unroll
        for (int j = 0; j < 8; ++j) mm[j] = mg[(size_t)j * N_DIM * 8];
        float tv[8];
#pragma unroll
        for (int j = 0; j < 8; ++j) tv[j] = mm[j] + v[j];
        float m = tv[0];
#pragma unroll
        for (int j = 1; j < 8; ++j) m = fmaxf(m, tv[j]);
        float ss = 0.0f;
#pragma unroll
        for (int j = 0; j < 8; ++j) ss += fexp2(tv[j] - m);
        const float nv = m + flog2(ss);
#pragma unroll
        for (int j = 0; j < 8; ++j) v[j] = __shfl(nv, j, 8);
    }
    float m = v[0];
#pragma unroll
    for (int j = 1; j < 8; ++j) m = fmaxf(m, v[j]);
    float ss = 0.0f;
#pragma unroll
    for (int j = 0; j < 8; ++j) ss += fexp2(v[j] - m);
    const float lz2 = m + flog2(ss);                 // base-2 logZ
    if (d == 0) corr[n] = lz2 * LN2_F / (float)T_DIM;
}

// ---------------------------------------------------------------------------
// K4: out[t][n][c] = f32(yb[t][n][c]) - corr[n]
// ---------------------------------------------------------------------------
__global__ __launch_bounds__(256) void k4_final(
    const unsigned short* __restrict__ yb, const float* __restrict__ corr,
    float* __restrict__ out)
{
    const int i = blockIdx.x * 256 + threadIdx.x;    // 8-elem group index
    const uint4 u = ((const uint4*)yb)[i];
    const float cr = corr[(i / 5) & (N_DIM - 1)];    // 5 groups per row
    float4 o0, o1;
    o0.x = bl(u.x) - cr; o0.y = bh(u.x) - cr;
    o0.z = bl(u.y) - cr; o0.w = bh(u.y) - cr;
    o1.x = bl(u.z) - cr; o1.y = bh(u.z) - cr;
    o1.z = bl(u.w) - cr; o1.w = bh(u.w) - cr;
    float4* o4 = (float4*)out;
    o4[i * 2]     = o0;
    o4[i * 2 + 1] = o1;
}

// ---------------------------------------------------------------------------
extern "C" void kernel_launch(void* const* d_in, const int* in_sizes, int n_in,
                              void* d_out, int out_size, void* d_ws, size_t ws_size,
                              hipStream_t stream)
{
    const float* x = (const float*)d_in[0];
    const float* W = (const float*)d_in[1];
    const float* b = (const float*)d_in[2];
    float* out = (float*)d_out;

    unsigned short* ybf = (unsigned short*)d_ws;              // 40 MB bf16 y
    float* cmat = (float*)((char*)d_ws + (48u << 20));        // 4 MB
    float* corr = cmat + (size_t)NCHUNK * 8 * N_DIM * 8;

    hipLaunchKernelGGL(k1_gemm_tanh, dim3(512),  dim3(256), 0, stream, x, W, b, ybf);
    hipLaunchKernelGGL(k2_chunks,    dim3(512),  dim3(256), 0, stream, ybf, cmat);
    hipLaunchKernelGGL(k3_combine,   dim3(8),    dim3(256), 0, stream, cmat, corr);
    hipLaunchKernelGGL(k4_final,     dim3(T_DIM * N_DIM * C_DIM / 8 / 256),
                       dim3(256), 0, stream, ybf, corr, out);
}